// Round 2
// baseline (288.224 us; speedup 1.0000x reference)
//
#include <hip/hip_runtime.h>

// ROI Align, reference-exact semantics.
// input: (N=8, C=256, H=100, W=100) fp32 NCHW
// rois:  (K=1000, 5) fp32  [batch, x1, y1, x2, y2] (image coords)
// out:   (K, C, 7, 7) fp32
//
// Round 0/1: one thread per output element (k,c,oh,ow). Stores coalesced;
// bilinear gathers rely on L1/L2/L3 (input fits in 256MB Infinity Cache).
// Round 1 resubmit: round 0 bench was an infra failure (GPU acquisition
// timeout) — no data, so no change. Need the baseline counters.

constexpr int   OUT_H = 7;
constexpr int   OUT_W = 7;
constexpr float SPATIAL_SCALE = 0.25f;
constexpr int   SR = 2;               // sampling ratio
constexpr int   C_DIM = 256;
constexpr int   H_DIM = 100;
constexpr int   W_DIM = 100;

__global__ __launch_bounds__(256) void roi_align_kernel(
    const float* __restrict__ input,
    const float* __restrict__ rois,
    float* __restrict__ out,
    int K)
{
    int idx = blockIdx.x * blockDim.x + threadIdx.x;
    int total = K * C_DIM * OUT_H * OUT_W;
    if (idx >= total) return;

    int ow = idx % OUT_W;
    int oh = (idx / OUT_W) % OUT_H;
    int c  = (idx / (OUT_W * OUT_H)) % C_DIM;
    int k  = idx / (OUT_W * OUT_H * C_DIM);

    const float* r = rois + (size_t)k * 5;
    int   b  = (int)r[0];
    float x1 = r[1] * SPATIAL_SCALE;
    float y1 = r[2] * SPATIAL_SCALE;
    float x2 = r[3] * SPATIAL_SCALE;
    float y2 = r[4] * SPATIAL_SCALE;

    float roi_w = fmaxf(x2 - x1, 1.0f);
    float roi_h = fmaxf(y2 - y1, 1.0f);
    float bin_h = roi_h / (float)OUT_H;
    float bin_w = roi_w / (float)OUT_W;

    const float* inp = input + ((size_t)b * C_DIM + c) * (H_DIM * W_DIM);

    float acc = 0.0f;
    #pragma unroll
    for (int sy = 0; sy < SR; ++sy) {
        float gy = y1 + bin_h * (((float)(oh * SR + sy) + 0.5f) / (float)SR);
        bool  vy = (gy >= -1.0f) && (gy <= (float)H_DIM);
        float y  = fminf(fmaxf(gy, 0.0f), (float)(H_DIM - 1));
        int   yl = (int)floorf(y);
        float ly = y - (float)yl;
        int   yh = min(yl + 1, H_DIM - 1);

        #pragma unroll
        for (int sx = 0; sx < SR; ++sx) {
            float gx = x1 + bin_w * (((float)(ow * SR + sx) + 0.5f) / (float)SR);
            bool  vx = (gx >= -1.0f) && (gx <= (float)W_DIM);
            float x  = fminf(fmaxf(gx, 0.0f), (float)(W_DIM - 1));
            int   xl = (int)floorf(x);
            float lx = x - (float)xl;
            int   xh = min(xl + 1, W_DIM - 1);

            float v_ll = inp[yl * W_DIM + xl];
            float v_lh = inp[yl * W_DIM + xh];
            float v_hl = inp[yh * W_DIM + xl];
            float v_hh = inp[yh * W_DIM + xh];

            float val = (1.0f - ly) * ((1.0f - lx) * v_ll + lx * v_lh)
                      +          ly  * ((1.0f - lx) * v_hl + lx * v_hh);
            if (vy && vx) acc += val;
        }
    }
    out[idx] = acc * 0.25f;
}

extern "C" void kernel_launch(void* const* d_in, const int* in_sizes, int n_in,
                              void* d_out, int out_size, void* d_ws, size_t ws_size,
                              hipStream_t stream) {
    const float* input = (const float*)d_in[0];
    const float* rois  = (const float*)d_in[1];
    float* out = (float*)d_out;

    int K = in_sizes[1] / 5;
    int total = K * C_DIM * OUT_H * OUT_W;
    int block = 256;
    int grid = (total + block - 1) / block;
    roi_align_kernel<<<grid, block, 0, stream>>>(input, rois, out, K);
}

// Round 3
// 213.680 us; speedup vs baseline: 1.3489x; 1.3489x over previous
//
#include <hip/hip_runtime.h>

// ROI Align on MI355X.
// input: (N=8, C=256, H=100, W=100) fp32 NCHW; rois (K,5); out (K,256,7,7) fp32.
//
// Round 3: NCHW gather was transaction-bound (FETCH 583MB vs 82MB input,
// 3.2 TB/s, VALU 36%). Fix: transpose to NHWC in d_ws, then gather with
// wave-per-bin / lane-per-4-channels so every bilinear corner is one fully
// coalesced 1KB float4 wave-load. Output staged in LDS (exact (C,7,7) layout)
// and copied out stride-1.

constexpr int   OUT_H = 7;
constexpr int   OUT_W = 7;
constexpr int   NBINS = OUT_H * OUT_W;          // 49
constexpr float SPATIAL_SCALE = 0.25f;
constexpr int   SR = 2;
constexpr int   N_DIM = 8;
constexpr int   C_DIM = 256;
constexpr int   H_DIM = 100;
constexpr int   W_DIM = 100;
constexpr int   HW    = H_DIM * W_DIM;          // 10000
constexpr size_t NHWC_BYTES = (size_t)N_DIM * HW * C_DIM * sizeof(float); // 81,920,000

// ---------------- transpose: NCHW (n, 256, 10000) -> NHWC (n, 10000, 256) ---
// Tile: 64 channels x 64 spatial, LDS staged, float4 both sides.
constexpr int TSTRIDE = 68;   // 64 + 4 pad (keeps float4 alignment, breaks bank stride)

__global__ __launch_bounds__(256) void nchw_to_nhwc(
    const float* __restrict__ in, float* __restrict__ out)
{
    __shared__ float tile[64 * TSTRIDE];
    int s0 = blockIdx.x * 64;          // spatial tile start (0..9984)
    int c0 = blockIdx.y * 64;          // channel tile start
    int n  = blockIdx.z;

    int t = threadIdx.x;
    int sl4 = (t & 15) * 4;            // spatial offset within tile, float4
    int cq  = t >> 4;                  // 0..15

    // load: rows = channels (coalesced along spatial)
    #pragma unroll
    for (int r = 0; r < 4; ++r) {
        int cl = r * 16 + cq;
        int s  = s0 + sl4;
        if (s < HW) {
            const float4 v = *(const float4*)(in + ((size_t)(n * C_DIM + c0 + cl) * HW + s));
            *(float4*)(tile + cl * TSTRIDE + sl4) = v;
        }
    }
    __syncthreads();

    // store: rows = spatial (coalesced along channels)
    int cl4 = (t & 15) * 4;
    #pragma unroll
    for (int r = 0; r < 4; ++r) {
        int sl = r * 16 + cq;
        int s  = s0 + sl;
        if (s < HW) {
            float4 v;
            v.x = tile[(cl4 + 0) * TSTRIDE + sl];
            v.y = tile[(cl4 + 1) * TSTRIDE + sl];
            v.z = tile[(cl4 + 2) * TSTRIDE + sl];
            v.w = tile[(cl4 + 3) * TSTRIDE + sl];
            *(float4*)(out + ((size_t)n * HW + s) * C_DIM + c0 + cl4) = v;
        }
    }
}

// ---------------- gather: one block per ROI, wave per bin, lane = 4 channels -
__global__ __launch_bounds__(256) void roi_gather_nhwc(
    const float* __restrict__ nhwc,
    const float* __restrict__ rois,
    float* __restrict__ out, int K)
{
    __shared__ float s_out[C_DIM * NBINS];   // exact (C,7,7) layout, 50176 B

    int k = blockIdx.x;
    const float* r = rois + (size_t)k * 5;
    int   b  = (int)r[0];
    float x1 = r[1] * SPATIAL_SCALE;
    float y1 = r[2] * SPATIAL_SCALE;
    float x2 = r[3] * SPATIAL_SCALE;
    float y2 = r[4] * SPATIAL_SCALE;
    float roi_w = fmaxf(x2 - x1, 1.0f);
    float roi_h = fmaxf(y2 - y1, 1.0f);
    float bin_h = roi_h / (float)OUT_H;
    float bin_w = roi_w / (float)OUT_W;

    int wave = threadIdx.x >> 6;
    int lane = threadIdx.x & 63;
    int cb   = lane * 4;

    const float* img = nhwc + (size_t)b * HW * C_DIM;

    for (int bin = wave; bin < NBINS; bin += 4) {
        int oh = bin / OUT_W;
        int ow = bin - oh * OUT_W;

        float ax = 0.f, ay = 0.f, az = 0.f, aw = 0.f;

        #pragma unroll
        for (int sy = 0; sy < SR; ++sy) {
            float gy = y1 + bin_h * (((float)(oh * SR + sy) + 0.5f) / (float)SR);
            bool  vy = (gy >= -1.0f) && (gy <= (float)H_DIM);
            float y  = fminf(fmaxf(gy, 0.0f), (float)(H_DIM - 1));
            int   yl = (int)floorf(y);
            float ly = y - (float)yl;
            int   yh = min(yl + 1, H_DIM - 1);

            #pragma unroll
            for (int sx = 0; sx < SR; ++sx) {
                float gx = x1 + bin_w * (((float)(ow * SR + sx) + 0.5f) / (float)SR);
                bool  vx = (gx >= -1.0f) && (gx <= (float)W_DIM);
                float x  = fminf(fmaxf(gx, 0.0f), (float)(W_DIM - 1));
                int   xl = (int)floorf(x);
                float lx = x - (float)xl;
                int   xh = min(xl + 1, W_DIM - 1);

                const float4 vll = *(const float4*)(img + ((size_t)(yl * W_DIM + xl) * C_DIM) + cb);
                const float4 vlh = *(const float4*)(img + ((size_t)(yl * W_DIM + xh) * C_DIM) + cb);
                const float4 vhl = *(const float4*)(img + ((size_t)(yh * W_DIM + xl) * C_DIM) + cb);
                const float4 vhh = *(const float4*)(img + ((size_t)(yh * W_DIM + xh) * C_DIM) + cb);

                float wll = (1.0f - ly) * (1.0f - lx);
                float wlh = (1.0f - ly) * lx;
                float whl = ly * (1.0f - lx);
                float whh = ly * lx;
                if (vy && vx) {
                    ax += wll * vll.x + wlh * vlh.x + whl * vhl.x + whh * vhh.x;
                    ay += wll * vll.y + wlh * vlh.y + whl * vhl.y + whh * vhh.y;
                    az += wll * vll.z + wlh * vlh.z + whl * vhl.z + whh * vhh.z;
                    aw += wll * vll.w + wlh * vlh.w + whl * vhl.w + whh * vhh.w;
                }
            }
        }
        // stage in (C,7,7) layout; 8-way bank conflict here is tiny volume
        s_out[(cb + 0) * NBINS + bin] = ax * 0.25f;
        s_out[(cb + 1) * NBINS + bin] = ay * 0.25f;
        s_out[(cb + 2) * NBINS + bin] = az * 0.25f;
        s_out[(cb + 3) * NBINS + bin] = aw * 0.25f;
    }
    __syncthreads();

    // coalesced copy-out: 12544 floats = 3136 float4
    float4* o4 = (float4*)(out + (size_t)k * (C_DIM * NBINS));
    const float4* s4 = (const float4*)s_out;
    for (int i = threadIdx.x; i < (C_DIM * NBINS) / 4; i += 256)
        o4[i] = s4[i];
}

// ---------------- fallback (round-0 baseline) if ws too small ---------------
__global__ __launch_bounds__(256) void roi_align_naive(
    const float* __restrict__ input, const float* __restrict__ rois,
    float* __restrict__ out, int K)
{
    int idx = blockIdx.x * blockDim.x + threadIdx.x;
    int total = K * C_DIM * OUT_H * OUT_W;
    if (idx >= total) return;
    int ow = idx % OUT_W;
    int oh = (idx / OUT_W) % OUT_H;
    int c  = (idx / (OUT_W * OUT_H)) % C_DIM;
    int k  = idx / (OUT_W * OUT_H * C_DIM);
    const float* r = rois + (size_t)k * 5;
    int   b  = (int)r[0];
    float x1 = r[1] * SPATIAL_SCALE, y1 = r[2] * SPATIAL_SCALE;
    float x2 = r[3] * SPATIAL_SCALE, y2 = r[4] * SPATIAL_SCALE;
    float roi_w = fmaxf(x2 - x1, 1.0f), roi_h = fmaxf(y2 - y1, 1.0f);
    float bin_h = roi_h / OUT_H, bin_w = roi_w / OUT_W;
    const float* inp = input + ((size_t)b * C_DIM + c) * HW;
    float acc = 0.0f;
    #pragma unroll
    for (int sy = 0; sy < SR; ++sy) {
        float gy = y1 + bin_h * (((float)(oh * SR + sy) + 0.5f) / SR);
        bool vy = (gy >= -1.0f) && (gy <= (float)H_DIM);
        float y = fminf(fmaxf(gy, 0.0f), (float)(H_DIM - 1));
        int yl = (int)floorf(y); float ly = y - yl; int yh = min(yl + 1, H_DIM - 1);
        #pragma unroll
        for (int sx = 0; sx < SR; ++sx) {
            float gx = x1 + bin_w * (((float)(ow * SR + sx) + 0.5f) / SR);
            bool vx = (gx >= -1.0f) && (gx <= (float)W_DIM);
            float x = fminf(fmaxf(gx, 0.0f), (float)(W_DIM - 1));
            int xl = (int)floorf(x); float lx = x - xl; int xh = min(xl + 1, W_DIM - 1);
            float v = (1.0f - ly) * ((1.0f - lx) * inp[yl * W_DIM + xl] + lx * inp[yl * W_DIM + xh])
                    + ly * ((1.0f - lx) * inp[yh * W_DIM + xl] + lx * inp[yh * W_DIM + xh]);
            if (vy && vx) acc += v;
        }
    }
    out[idx] = acc * 0.25f;
}

extern "C" void kernel_launch(void* const* d_in, const int* in_sizes, int n_in,
                              void* d_out, int out_size, void* d_ws, size_t ws_size,
                              hipStream_t stream) {
    const float* input = (const float*)d_in[0];
    const float* rois  = (const float*)d_in[1];
    float* out = (float*)d_out;
    int K = in_sizes[1] / 5;

    if (ws_size >= NHWC_BYTES) {
        float* nhwc = (float*)d_ws;
        dim3 tgrid((HW + 63) / 64, C_DIM / 64, N_DIM);   // 157 x 4 x 8
        nchw_to_nhwc<<<tgrid, 256, 0, stream>>>(input, nhwc);
        roi_gather_nhwc<<<K, 256, 0, stream>>>(nhwc, rois, out, K);
    } else {
        int total = K * C_DIM * OUT_H * OUT_W;
        roi_align_naive<<<(total + 255) / 256, 256, 0, stream>>>(input, rois, out, K);
    }
}